// Round 5
// baseline (403.469 us; speedup 1.0000x reference)
//
#include <hip/hip_runtime.h>
#include <math.h>

#define NEG_SLOPE 0.2f
__device__ __forceinline__ float leaky(float x) { return x > 0.f ? x : NEG_SLOPE * x; }

typedef _Float16 f16;
typedef _Float16 f16x2 __attribute__((ext_vector_type(2)));
typedef _Float16 f16x4 __attribute__((ext_vector_type(4)));
typedef _Float16 f16x8 __attribute__((ext_vector_type(8)));
typedef float f32x4 __attribute__((ext_vector_type(4)));

__device__ __forceinline__ int kmap(int lh, int e) {
  return (e < 4) ? lh * 4 + e : 16 + lh * 4 + (e - 4);
}

// ---------------- CSR build ----------------
__global__ void k_count(const int* __restrict__ dst, int* __restrict__ deg, int E) {
  int e = blockIdx.x * blockDim.x + threadIdx.x;
  if (e < E) atomicAdd(&deg[dst[e]], 1);
}

__global__ __launch_bounds__(256) void k_partial(const int* __restrict__ deg,
                                                 int* __restrict__ part, int n) {
  __shared__ int s[256];
  int i = blockIdx.x * 256 + threadIdx.x;
  s[threadIdx.x] = (i < n) ? deg[i] : 0;
  __syncthreads();
  for (int off = 128; off > 0; off >>= 1) {
    if (threadIdx.x < off) s[threadIdx.x] += s[threadIdx.x + off];
    __syncthreads();
  }
  if (threadIdx.x == 0) part[blockIdx.x] = s[0];
}

__global__ __launch_bounds__(256) void k_scanpart(int* __restrict__ part, int nb) {
  __shared__ int s[256];
  int t = threadIdx.x;
  int v = (t < nb) ? part[t] : 0;
  s[t] = v;
  __syncthreads();
  for (int off = 1; off < 256; off <<= 1) {
    int u = (t >= off) ? s[t - off] : 0;
    __syncthreads();
    s[t] += u;
    __syncthreads();
  }
  if (t < nb) part[t] = s[t] - v;
}

// also zeroes cursor (deg) for the fill pass
__global__ __launch_bounds__(256) void k_offs(int* __restrict__ deg,
                                              const int* __restrict__ part,
                                              int* __restrict__ offs, int n) {
  __shared__ int s[256];
  int i = blockIdx.x * 256 + threadIdx.x;
  int v = (i < n) ? deg[i] : 0;
  s[threadIdx.x] = v;
  __syncthreads();
  for (int off = 1; off < 256; off <<= 1) {
    int u = (threadIdx.x >= off) ? s[threadIdx.x - off] : 0;
    __syncthreads();
    s[threadIdx.x] += u;
    __syncthreads();
  }
  int excl = part[blockIdx.x] + s[threadIdx.x] - v;
  if (i < n) {
    offs[i] = excl;
    deg[i] = 0;  // reset cursor for k_fill
  }
  if (i == n - 1) offs[n] = excl + v;
}

__global__ void k_fill(const int* __restrict__ src, const int* __restrict__ dst,
                       const int* __restrict__ offs, int* __restrict__ cursor,
                       int* __restrict__ col, int E) {
  int e = blockIdx.x * blockDim.x + threadIdx.x;
  if (e >= E) return;
  int d = dst[e];
  int pos = atomicAdd(&cursor[d], 1);
  col[offs[d] + pos] = src[e];
}

// ---------------- pack W1 (+ folded alpha vectors) into B-fragment order ----------------
__global__ __launch_bounds__(256) void k_packw1(const float* __restrict__ W1,
    const float* __restrict__ a_src, const float* __restrict__ a_dst,
    f16* __restrict__ Wp1) {
  int tid = blockIdx.x * 256 + threadIdx.x;
  if (tid >= 17 * 4 * 64 * 8) return;
  int e = tid & 7, l = (tid >> 3) & 63, ks = (tid >> 9) & 3, nt = tid >> 11;
  int lh = l >> 4, li = l & 15;
  int k = ks * 32 + kmap(lh, e);
  float v;
  if (nt < 16) {
    v = W1[k * 256 + nt * 16 + li];
  } else {
    int h = li & 7;
    const float* a = (li < 8) ? (a_src + h * 32) : (a_dst + h * 32);
    v = 0.f;
    for (int j = 0; j < 32; ++j) v += W1[k * 256 + h * 32 + j] * a[j];
  }
  Wp1[tid] = (f16)v;
}

__global__ __launch_bounds__(256) void k_packw2(const float* __restrict__ W2,
    const float* __restrict__ a_src, const float* __restrict__ a_dst,
    f16* __restrict__ Wp2) {
  int tid = blockIdx.x * 256 + threadIdx.x;
  if (tid >= 5 * 8 * 64 * 8) return;
  int e = tid & 7, l = (tid >> 3) & 63, ks = (tid >> 9) & 7, nt = tid >> 12;
  int lh = l >> 4, li = l & 15;
  int k = ks * 32 + kmap(lh, e);
  float v = 0.f;
  if (nt < 4) {
    v = W2[k * 64 + nt * 16 + li];
  } else if (li == 0) {
    for (int j = 0; j < 64; ++j) v += W2[k * 64 + j] * a_src[j];
  } else if (li == 1) {
    for (int j = 0; j < 64; ++j) v += W2[k * 64 + j] * a_dst[j];
  }
  Wp2[tid] = (f16)v;
}

// ---------------- MFMA GEMM1: [N,128]@[128,256], fp32 X in-reg cvt, fused alpha (transposed) ----------------
__global__ __launch_bounds__(256) void k_gemm1(const float* __restrict__ x,
    const f16* __restrict__ Wp1, f16* __restrict__ h16,
    float* __restrict__ as_t, float* __restrict__ ad_t, int n, int nWaves) {
  int wid = blockIdx.x * 4 + (threadIdx.x >> 6);
  if (wid >= nWaves) return;
  int lane = threadIdx.x & 63, lh = lane >> 4, li = lane & 15;
  size_t arow = (size_t)min(wid * 16 + li, n - 1);
  f16x8 a[4];
#pragma unroll
  for (int ks = 0; ks < 4; ++ks) {
    float4 lo = *(const float4*)&x[arow * 128 + ks * 32 + lh * 4];
    float4 hi = *(const float4*)&x[arow * 128 + ks * 32 + 16 + lh * 4];
    a[ks][0] = (f16)lo.x; a[ks][1] = (f16)lo.y; a[ks][2] = (f16)lo.z; a[ks][3] = (f16)lo.w;
    a[ks][4] = (f16)hi.x; a[ks][5] = (f16)hi.y; a[ks][6] = (f16)hi.z; a[ks][7] = (f16)hi.w;
  }
  int rbase = wid * 16 + lh * 4;
#pragma unroll
  for (int nt = 0; nt < 17; ++nt) {
    f32x4 acc = {0.f, 0.f, 0.f, 0.f};
#pragma unroll
    for (int ks = 0; ks < 4; ++ks) {
      f16x8 b = *(const f16x8*)&Wp1[((nt * 4 + ks) * 64 + lane) * 8];
      acc = __builtin_amdgcn_mfma_f32_16x16x32_f16(a[ks], b, acc, 0, 0, 0);
    }
    if (nt < 16) {
#pragma unroll
      for (int r = 0; r < 4; ++r) {
        int rr = rbase + r;
        if (rr < n) h16[(size_t)rr * 256 + nt * 16 + li] = (f16)acc[r];
      }
    } else {
#pragma unroll
      for (int r = 0; r < 4; ++r) {
        int rr = rbase + r;
        if (rr < n) {
          if (li < 8) as_t[(size_t)li * n + rr] = acc[r];
          else        ad_t[(size_t)(li - 8) * n + rr] = acc[r];
        }
      }
    }
  }
}

// ---------------- MFMA GEMM2: [N,256]@[256,64] + fused alpha ----------------
__global__ __launch_bounds__(256) void k_gemm2(const f16* __restrict__ R16,
    const f16* __restrict__ Wp2, f16* __restrict__ h2,
    float* __restrict__ as, float* __restrict__ ad, int n, int nWaves) {
  int wid = blockIdx.x * 4 + (threadIdx.x >> 6);
  if (wid >= nWaves) return;
  int lane = threadIdx.x & 63, lh = lane >> 4, li = lane & 15;
  size_t arow = (size_t)min(wid * 16 + li, n - 1);
  f16x8 a[8];
#pragma unroll
  for (int ks = 0; ks < 8; ++ks) {
    f16x4 lo = *(const f16x4*)&R16[arow * 256 + ks * 32 + lh * 4];
    f16x4 hi = *(const f16x4*)&R16[arow * 256 + ks * 32 + 16 + lh * 4];
    a[ks][0] = lo[0]; a[ks][1] = lo[1]; a[ks][2] = lo[2]; a[ks][3] = lo[3];
    a[ks][4] = hi[0]; a[ks][5] = hi[1]; a[ks][6] = hi[2]; a[ks][7] = hi[3];
  }
  int rbase = wid * 16 + lh * 4;
#pragma unroll
  for (int nt = 0; nt < 5; ++nt) {
    f32x4 acc = {0.f, 0.f, 0.f, 0.f};
#pragma unroll
    for (int ks = 0; ks < 8; ++ks) {
      f16x8 b = *(const f16x8*)&Wp2[((nt * 8 + ks) * 64 + lane) * 8];
      acc = __builtin_amdgcn_mfma_f32_16x16x32_f16(a[ks], b, acc, 0, 0, 0);
    }
    if (nt < 4) {
#pragma unroll
      for (int r = 0; r < 4; ++r) {
        int rr = rbase + r;
        if (rr < n) h2[(size_t)rr * 64 + nt * 16 + li] = (f16)acc[r];
      }
    } else {
#pragma unroll
      for (int r = 0; r < 4; ++r) {
        int rr = rbase + r;
        if (rr < n) {
          if (li == 0) as[rr] = acc[r];
          else if (li == 1) ad[rr] = acc[r];
        }
      }
    }
  }
}

// ---------------- Layer 1 aggregation: XCD-sliced 32-ch, 8 edges in flight ----------------
// grid = nodeBlocks*8; slice = blockIdx&7 (== head); wave = one node; lane = es(4)*16 + c(16)
__global__ __launch_bounds__(256) void k_agg1(const f16* __restrict__ h16,
    const float* __restrict__ as_t, const float* __restrict__ ad_t,
    const int* __restrict__ offs, const int* __restrict__ col,
    const float* __restrict__ b, f16* __restrict__ out, int n) {
  int slice = blockIdx.x & 7;
  int node = (blockIdx.x >> 3) * 4 + (threadIdx.x >> 6);
  if (node >= n) return;
  node = __builtin_amdgcn_readfirstlane(node);
  int lane = threadIdx.x & 63;
  int es = lane >> 4;   // 0..3 edge slot
  int c = lane & 15;    // channel pair
  int beg = offs[node], end = offs[node + 1];
  int deg = end - beg;
  const float* asl = as_t + (size_t)slice * n;
  float adn = ad_t[(size_t)slice * n + node];
  const f16* hs = h16 + slice * 32 + c * 2;

  float accx = 0.f, accy = 0.f, wsum = 0.f;
  if (es == 0) {  // self-loop handled once
    float w = __expf(leaky(asl[node] + adn));
    f16x2 g = *(const f16x2*)&hs[(size_t)node * 256];
    accx = w * (float)g[0]; accy = w * (float)g[1]; wsum = w;
  }
  for (int base = 0; base < deg; base += 8) {
    int iA = base + es, iB = iA + 4;
    int sA = (iA < deg) ? col[beg + iA] : node;
    int sB = (iB < deg) ? col[beg + iB] : node;
    float wA = (iA < deg) ? __expf(leaky(asl[sA] + adn)) : 0.f;
    float wB = (iB < deg) ? __expf(leaky(asl[sB] + adn)) : 0.f;
    f16x2 gA = *(const f16x2*)&hs[(size_t)sA * 256];
    f16x2 gB = *(const f16x2*)&hs[(size_t)sB * 256];
    accx += wA * (float)gA[0] + wB * (float)gB[0];
    accy += wA * (float)gA[1] + wB * (float)gB[1];
    wsum += wA + wB;
  }
  accx += __shfl_xor(accx, 16, 64);
  accy += __shfl_xor(accy, 16, 64);
  wsum += __shfl_xor(wsum, 16, 64);
  accx += __shfl_xor(accx, 32, 64);
  accy += __shfl_xor(accy, 32, 64);
  wsum += __shfl_xor(wsum, 32, 64);
  if (es == 0) {
    float inv = 1.f / wsum;
    int ch = slice * 32 + c * 2;
    float2 bv = *(const float2*)&b[ch];
    f16x2 o;
    o[0] = (f16)fmaxf(fmaf(accx, inv, bv.x), 0.f);
    o[1] = (f16)fmaxf(fmaf(accy, inv, bv.y), 0.f);
    *(f16x2*)&out[(size_t)node * 256 + ch] = o;
  }
}

// ---------------- Layer 2 aggregation: 2 slices of 32 ch, 8 edges in flight ----------------
// grid = nodeBlocks*2; slice = blockIdx&1
__global__ __launch_bounds__(256) void k_agg2(const f16* __restrict__ h2,
    const float* __restrict__ as, const float* __restrict__ ad,
    const int* __restrict__ offs, const int* __restrict__ col,
    const float* __restrict__ b, float* __restrict__ out, int n) {
  int slice = blockIdx.x & 1;
  int node = (blockIdx.x >> 1) * 4 + (threadIdx.x >> 6);
  if (node >= n) return;
  node = __builtin_amdgcn_readfirstlane(node);
  int lane = threadIdx.x & 63;
  int es = lane >> 4;
  int c = lane & 15;
  int beg = offs[node], end = offs[node + 1];
  int deg = end - beg;
  float adn = ad[node];
  const f16* hs = h2 + slice * 32 + c * 2;

  float accx = 0.f, accy = 0.f, wsum = 0.f;
  if (es == 0) {
    float w = __expf(leaky(as[node] + adn));
    f16x2 g = *(const f16x2*)&hs[(size_t)node * 64];
    accx = w * (float)g[0]; accy = w * (float)g[1]; wsum = w;
  }
  for (int base = 0; base < deg; base += 8) {
    int iA = base + es, iB = iA + 4;
    int sA = (iA < deg) ? col[beg + iA] : node;
    int sB = (iB < deg) ? col[beg + iB] : node;
    float wA = (iA < deg) ? __expf(leaky(as[sA] + adn)) : 0.f;
    float wB = (iB < deg) ? __expf(leaky(as[sB] + adn)) : 0.f;
    f16x2 gA = *(const f16x2*)&hs[(size_t)sA * 64];
    f16x2 gB = *(const f16x2*)&hs[(size_t)sB * 64];
    accx += wA * (float)gA[0] + wB * (float)gB[0];
    accy += wA * (float)gA[1] + wB * (float)gB[1];
    wsum += wA + wB;
  }
  accx += __shfl_xor(accx, 16, 64);
  accy += __shfl_xor(accy, 16, 64);
  wsum += __shfl_xor(wsum, 16, 64);
  accx += __shfl_xor(accx, 32, 64);
  accy += __shfl_xor(accy, 32, 64);
  wsum += __shfl_xor(wsum, 32, 64);
  if (es == 0) {
    float inv = 1.f / wsum;
    int ch = slice * 32 + c * 2;
    float2 bv = *(const float2*)&b[ch];
    float2 o;
    o.x = fmaxf(fmaf(accx, inv, bv.x), 0.f);
    o.y = fmaxf(fmaf(accy, inv, bv.y), 0.f);
    *(float2*)&out[(size_t)node * 64 + ch] = o;
  }
}

extern "C" void kernel_launch(void* const* d_in, const int* in_sizes, int n_in,
                              void* d_out, int out_size, void* d_ws, size_t ws_size,
                              hipStream_t stream) {
  const float* x      = (const float*)d_in[0];
  const int*   ei     = (const int*)d_in[1];
  const float* W1     = (const float*)d_in[2];
  const float* a_src1 = (const float*)d_in[3];
  const float* a_dst1 = (const float*)d_in[4];
  const float* b1     = (const float*)d_in[5];
  const float* W2     = (const float*)d_in[6];
  const float* a_src2 = (const float*)d_in[7];
  const float* a_dst2 = (const float*)d_in[8];
  const float* b2     = (const float*)d_in[9];

  int N = in_sizes[0] / 128;
  int E = in_sizes[1] / 2;
  const int* srcI = ei;
  const int* dstI = ei + E;
  int nb = (N + 255) / 256;
  int nWaves = (N + 15) / 16;
  int nodeBlocks = (N + 3) / 4;

  char* ws = (char*)d_ws;
  size_t o = 0;
  auto alloc = [&](size_t bytes) -> void* {
    void* p = ws + o;
    o += (bytes + 255) & ~(size_t)255;
    return p;
  };
  f16*   h1f    = (f16*)alloc((size_t)N * 256 * 2);
  f16*   r16    = (f16*)alloc((size_t)N * 256 * 2);
  f16*   h2f    = (f16*)alloc((size_t)N * 64 * 2);
  f16*   Wp1    = (f16*)alloc((size_t)17 * 4 * 64 * 8 * 2);
  f16*   Wp2    = (f16*)alloc((size_t)5 * 8 * 64 * 8 * 2);
  float* as1    = (float*)alloc((size_t)8 * N * 4);   // transposed [head][node]
  float* ad1    = (float*)alloc((size_t)8 * N * 4);
  float* as2    = (float*)alloc((size_t)N * 4);
  float* ad2    = (float*)alloc((size_t)N * 4);
  int*   offs   = (int*)alloc((size_t)(N + 1) * 4);
  int*   cursor = (int*)alloc((size_t)N * 4);
  int*   col    = (int*)alloc((size_t)E * 4);
  int*   part   = (int*)alloc((size_t)nb * 4);

  // CSR by dst (self-loops implicit in agg kernels)
  hipMemsetAsync(cursor, 0, (size_t)N * 4, stream);
  k_count<<<(E + 255) / 256, 256, 0, stream>>>(dstI, cursor, E);
  k_partial<<<nb, 256, 0, stream>>>(cursor, part, N);
  k_scanpart<<<1, 256, 0, stream>>>(part, nb);
  k_offs<<<nb, 256, 0, stream>>>(cursor, part, offs, N);  // also zeroes cursor
  k_fill<<<(E + 255) / 256, 256, 0, stream>>>(srcI, dstI, offs, cursor, col, E);

  // weight packs
  k_packw1<<<(17 * 4 * 64 * 8 + 255) / 256, 256, 0, stream>>>(W1, a_src1, a_dst1, Wp1);
  k_packw2<<<(5 * 8 * 64 * 8 + 255) / 256, 256, 0, stream>>>(W2, a_src2, a_dst2, Wp2);

  // Layer 1
  k_gemm1<<<(nWaves + 3) / 4, 256, 0, stream>>>(x, Wp1, h1f, as1, ad1, N, nWaves);
  k_agg1<<<nodeBlocks * 8, 256, 0, stream>>>(h1f, as1, ad1, offs, col, b1, r16, N);

  // Layer 2
  k_gemm2<<<(nWaves + 3) / 4, 256, 0, stream>>>(r16, Wp2, h2f, as2, ad2, N, nWaves);
  k_agg2<<<nodeBlocks * 2, 256, 0, stream>>>(h2f, as2, ad2, offs, col, b2, (float*)d_out, N);
}

// Round 7
// 222.705 us; speedup vs baseline: 1.8117x; 1.8117x over previous
//
#include <hip/hip_runtime.h>
#include <math.h>

#define NEG_SLOPE 0.2f
__device__ __forceinline__ float leaky(float x) { return fmaxf(x, NEG_SLOPE * x); }

typedef _Float16 f16;
typedef _Float16 f16x2 __attribute__((ext_vector_type(2)));
typedef _Float16 f16x4 __attribute__((ext_vector_type(4)));
typedef _Float16 f16x8 __attribute__((ext_vector_type(8)));
typedef float f32x4 __attribute__((ext_vector_type(4)));

__device__ __forceinline__ int kmap(int lh, int e) {
  return (e < 4) ? lh * 4 + e : 16 + lh * 4 + (e - 4);
}

// ---------------- CSR build ----------------
__global__ void k_count(const int* __restrict__ dst, int* __restrict__ deg, int E) {
  int e = blockIdx.x * blockDim.x + threadIdx.x;
  if (e < E) atomicAdd(&deg[dst[e]], 1);
}

__global__ __launch_bounds__(256) void k_partial(const int* __restrict__ deg,
                                                 int* __restrict__ part, int n) {
  __shared__ int s[256];
  int i = blockIdx.x * 256 + threadIdx.x;
  s[threadIdx.x] = (i < n) ? deg[i] : 0;
  __syncthreads();
  for (int off = 128; off > 0; off >>= 1) {
    if (threadIdx.x < off) s[threadIdx.x] += s[threadIdx.x + off];
    __syncthreads();
  }
  if (threadIdx.x == 0) part[blockIdx.x] = s[0];
}

// scans partials redundantly per block (nb<=256), then block-local exclusive scan.
// also zeroes deg (cursor) for the fill pass.
__global__ __launch_bounds__(256) void k_offs(int* __restrict__ deg,
                                              const int* __restrict__ part,
                                              int* __restrict__ offs, int n, int nb) {
  __shared__ int ps[256];
  __shared__ int s[256];
  int t = threadIdx.x;
  ps[t] = (t < nb) ? part[t] : 0;
  __syncthreads();
  for (int off = 1; off < 256; off <<= 1) {
    int u = (t >= off) ? ps[t - off] : 0;
    __syncthreads();
    ps[t] += u;
    __syncthreads();
  }
  int base = (blockIdx.x > 0) ? ps[blockIdx.x - 1] : 0;

  int i = blockIdx.x * 256 + t;
  int v = (i < n) ? deg[i] : 0;
  s[t] = v;
  __syncthreads();
  for (int off = 1; off < 256; off <<= 1) {
    int u = (t >= off) ? s[t - off] : 0;
    __syncthreads();
    s[t] += u;
    __syncthreads();
  }
  int excl = base + s[t] - v;
  if (i < n) {
    offs[i] = excl;
    deg[i] = 0;  // reset cursor for k_fill
  }
  if (i == n - 1) offs[n] = excl + v;
}

__global__ void k_fill(const int* __restrict__ src, const int* __restrict__ dst,
                       const int* __restrict__ offs, int* __restrict__ cursor,
                       int* __restrict__ col, int E) {
  int e = blockIdx.x * blockDim.x + threadIdx.x;
  if (e >= E) return;
  int d = dst[e];
  int pos = atomicAdd(&cursor[d], 1);
  col[offs[d] + pos] = src[e];
}

// ---------------- merged weight pack (W1 + folded alphas | W2 + folded alphas) ----------------
#define W1_TOT (17 * 4 * 64 * 8)
#define W2_TOT (5 * 8 * 64 * 8)
__global__ __launch_bounds__(256) void k_packw(const float* __restrict__ W1,
    const float* __restrict__ as1, const float* __restrict__ ad1,
    const float* __restrict__ W2, const float* __restrict__ as2,
    const float* __restrict__ ad2, f16* __restrict__ Wp1, f16* __restrict__ Wp2) {
  int tid = blockIdx.x * 256 + threadIdx.x;
  if (tid < W1_TOT) {
    int e = tid & 7, l = (tid >> 3) & 63, ks = (tid >> 9) & 3, nt = tid >> 11;
    int lh = l >> 4, li = l & 15;
    int k = ks * 32 + kmap(lh, e);
    float v;
    if (nt < 16) {
      v = W1[k * 256 + nt * 16 + li];
    } else {
      int h = li & 7;
      const float* a = (li < 8) ? (as1 + h * 32) : (ad1 + h * 32);
      v = 0.f;
      for (int j = 0; j < 32; ++j) v += W1[k * 256 + h * 32 + j] * a[j];
    }
    Wp1[tid] = (f16)v;
  } else if (tid < W1_TOT + W2_TOT) {
    int t2 = tid - W1_TOT;
    int e = t2 & 7, l = (t2 >> 3) & 63, ks = (t2 >> 9) & 7, nt = t2 >> 12;
    int lh = l >> 4, li = l & 15;
    int k = ks * 32 + kmap(lh, e);
    float v = 0.f;
    if (nt < 4) {
      v = W2[k * 64 + nt * 16 + li];
    } else if (li == 0) {
      for (int j = 0; j < 64; ++j) v += W2[k * 64 + j] * as2[j];
    } else if (li == 1) {
      for (int j = 0; j < 64; ++j) v += W2[k * 64 + j] * ad2[j];
    }
    Wp2[t2] = (f16)v;
  }
}

// ---------------- MFMA GEMM1: [N,128]@[128,256], fp32 X in-reg cvt, fused alpha ----------------
// 2 waves per 16-row tile: half0 -> nt 0..7, half1 -> nt 8..16 (incl alpha tile)
__global__ __launch_bounds__(256) void k_gemm1(const float* __restrict__ x,
    const f16* __restrict__ Wp1, f16* __restrict__ h16,
    float* __restrict__ as, float* __restrict__ ad, int n, int nSlots) {
  int slot = blockIdx.x * 4 + (threadIdx.x >> 6);
  if (slot >= nSlots) return;
  int half = slot & 1;
  int wid = slot >> 1;
  int lane = threadIdx.x & 63, lh = lane >> 4, li = lane & 15;
  size_t arow = (size_t)min(wid * 16 + li, n - 1);
  f16x8 a[4];
#pragma unroll
  for (int ks = 0; ks < 4; ++ks) {
    float4 lo = *(const float4*)&x[arow * 128 + ks * 32 + lh * 4];
    float4 hi = *(const float4*)&x[arow * 128 + ks * 32 + 16 + lh * 4];
    a[ks][0] = (f16)lo.x; a[ks][1] = (f16)lo.y; a[ks][2] = (f16)lo.z; a[ks][3] = (f16)lo.w;
    a[ks][4] = (f16)hi.x; a[ks][5] = (f16)hi.y; a[ks][6] = (f16)hi.z; a[ks][7] = (f16)hi.w;
  }
  int rbase = wid * 16 + lh * 4;
  int ntBeg = half ? 8 : 0;
  int ntEnd = half ? 17 : 8;
  for (int nt = ntBeg; nt < ntEnd; ++nt) {
    f32x4 acc = {0.f, 0.f, 0.f, 0.f};
#pragma unroll
    for (int ks = 0; ks < 4; ++ks) {
      f16x8 b = *(const f16x8*)&Wp1[((nt * 4 + ks) * 64 + lane) * 8];
      acc = __builtin_amdgcn_mfma_f32_16x16x32_f16(a[ks], b, acc, 0, 0, 0);
    }
    if (nt < 16) {
#pragma unroll
      for (int r = 0; r < 4; ++r) {
        int rr = rbase + r;
        if (rr < n) h16[(size_t)rr * 256 + nt * 16 + li] = (f16)acc[r];
      }
    } else {
#pragma unroll
      for (int r = 0; r < 4; ++r) {
        int rr = rbase + r;
        if (rr < n) {
          if (li < 8) as[(size_t)rr * 8 + li] = acc[r];
          else        ad[(size_t)rr * 8 + (li - 8)] = acc[r];
        }
      }
    }
  }
}

// ---------------- MFMA GEMM2: [N,256]@[256,64] + fused alpha ----------------
__global__ __launch_bounds__(256) void k_gemm2(const f16* __restrict__ R16,
    const f16* __restrict__ Wp2, f16* __restrict__ h2,
    float* __restrict__ as, float* __restrict__ ad, int n, int nWaves) {
  int wid = blockIdx.x * 4 + (threadIdx.x >> 6);
  if (wid >= nWaves) return;
  int lane = threadIdx.x & 63, lh = lane >> 4, li = lane & 15;
  size_t arow = (size_t)min(wid * 16 + li, n - 1);
  f16x8 a[8];
#pragma unroll
  for (int ks = 0; ks < 8; ++ks) {
    f16x4 lo = *(const f16x4*)&R16[arow * 256 + ks * 32 + lh * 4];
    f16x4 hi = *(const f16x4*)&R16[arow * 256 + ks * 32 + 16 + lh * 4];
    a[ks][0] = lo[0]; a[ks][1] = lo[1]; a[ks][2] = lo[2]; a[ks][3] = lo[3];
    a[ks][4] = hi[0]; a[ks][5] = hi[1]; a[ks][6] = hi[2]; a[ks][7] = hi[3];
  }
  int rbase = wid * 16 + lh * 4;
#pragma unroll
  for (int nt = 0; nt < 5; ++nt) {
    f32x4 acc = {0.f, 0.f, 0.f, 0.f};
#pragma unroll
    for (int ks = 0; ks < 8; ++ks) {
      f16x8 b = *(const f16x8*)&Wp2[((nt * 8 + ks) * 64 + lane) * 8];
      acc = __builtin_amdgcn_mfma_f32_16x16x32_f16(a[ks], b, acc, 0, 0, 0);
    }
    if (nt < 4) {
#pragma unroll
      for (int r = 0; r < 4; ++r) {
        int rr = rbase + r;
        if (rr < n) h2[(size_t)rr * 64 + nt * 16 + li] = (f16)acc[r];
      }
    } else {
#pragma unroll
      for (int r = 0; r < 4; ++r) {
        int rr = rbase + r;
        if (rr < n) {
          if (li == 0) as[rr] = acc[r];
          else if (li == 1) ad[rr] = acc[r];
        }
      }
    }
  }
}

// ---------------- Layer 1 aggregation: wave/node, 8 edges in flight, fp16 gather ----------------
__global__ __launch_bounds__(256) void k_agg1(const f16* __restrict__ h16,
    const float* __restrict__ as, const float* __restrict__ ad,
    const int* __restrict__ offs, const int* __restrict__ col,
    const float* __restrict__ b, f16* __restrict__ out, int n) {
  int node = blockIdx.x * 4 + (threadIdx.x >> 6);
  if (node >= n) return;
  node = __builtin_amdgcn_readfirstlane(node);
  int lane = threadIdx.x & 63;
  int head = lane >> 3;
  int c0 = lane * 4;
  int beg = offs[node], end = offs[node + 1];
  float adn = ad[node * 8 + head];

  float denom, ax, ay, az, aw;
  {  // self-loop
    float w = __expf(leaky(as[node * 8 + head] + adn));
    f16x4 g = *(const f16x4*)&h16[(size_t)node * 256 + c0];
    denom = w;
    ax = w * (float)g[0]; ay = w * (float)g[1];
    az = w * (float)g[2]; aw = w * (float)g[3];
  }
  int p = beg;
  for (; p + 8 <= end; p += 8) {
    int s[8];
#pragma unroll
    for (int j = 0; j < 8; ++j) s[j] = col[p + j];  // uniform -> s_load
    float e[8];
#pragma unroll
    for (int j = 0; j < 8; ++j) e[j] = as[s[j] * 8 + head];
    f16x4 g[8];
#pragma unroll
    for (int j = 0; j < 8; ++j) g[j] = *(const f16x4*)&h16[(size_t)s[j] * 256 + c0];
    float w[8];
#pragma unroll
    for (int j = 0; j < 8; ++j) w[j] = __expf(leaky(e[j] + adn));
#pragma unroll
    for (int j = 0; j < 8; ++j) {
      denom += w[j];
      ax += w[j] * (float)g[j][0]; ay += w[j] * (float)g[j][1];
      az += w[j] * (float)g[j][2]; aw += w[j] * (float)g[j][3];
    }
  }
  for (; p < end; ++p) {
    int s = col[p];
    float w = __expf(leaky(as[s * 8 + head] + adn));
    f16x4 g = *(const f16x4*)&h16[(size_t)s * 256 + c0];
    denom += w;
    ax += w * (float)g[0]; ay += w * (float)g[1];
    az += w * (float)g[2]; aw += w * (float)g[3];
  }
  float inv = 1.f / denom;
  float4 bv = *(const float4*)&b[c0];
  f16x4 o;
  o[0] = (f16)fmaxf(fmaf(ax, inv, bv.x), 0.f);
  o[1] = (f16)fmaxf(fmaf(ay, inv, bv.y), 0.f);
  o[2] = (f16)fmaxf(fmaf(az, inv, bv.z), 0.f);
  o[3] = (f16)fmaxf(fmaf(aw, inv, bv.w), 0.f);
  __builtin_nontemporal_store(o, (f16x4*)&out[(size_t)node * 256 + c0]);
}

// ---------------- Layer 2 aggregation: wave/node, 4 edge-slots x 16 lanes, 8 in flight ----------------
__global__ __launch_bounds__(256) void k_agg2(const f16* __restrict__ h2,
    const float* __restrict__ as, const float* __restrict__ ad,
    const int* __restrict__ offs, const int* __restrict__ col,
    const float* __restrict__ b, float* __restrict__ out, int n) {
  int node = blockIdx.x * 4 + (threadIdx.x >> 6);
  if (node >= n) return;
  node = __builtin_amdgcn_readfirstlane(node);
  int lane = threadIdx.x & 63;
  int es = lane >> 4;   // edge slot 0..3
  int c = lane & 15;    // channel quad: ch = c*4
  int beg = offs[node], end = offs[node + 1];
  int deg = end - beg;
  float adn = ad[node];

  float a0 = 0.f, a1 = 0.f, a2 = 0.f, a3 = 0.f, wsum = 0.f;
  if (es == 0) {  // self-loop once
    float w = __expf(leaky(as[node] + adn));
    f16x4 g = *(const f16x4*)&h2[(size_t)node * 64 + c * 4];
    wsum = w;
    a0 = w * (float)g[0]; a1 = w * (float)g[1];
    a2 = w * (float)g[2]; a3 = w * (float)g[3];
  }
  for (int base = 0; base < deg; base += 8) {
    int iA = base + es, iB = iA + 4;
    int sA = (iA < deg) ? col[beg + iA] : node;
    int sB = (iB < deg) ? col[beg + iB] : node;
    float eA = as[sA], eB = as[sB];
    f16x4 gA = *(const f16x4*)&h2[(size_t)sA * 64 + c * 4];
    f16x4 gB = *(const f16x4*)&h2[(size_t)sB * 64 + c * 4];
    float wA = (iA < deg) ? __expf(leaky(eA + adn)) : 0.f;
    float wB = (iB < deg) ? __expf(leaky(eB + adn)) : 0.f;
    wsum += wA + wB;
    a0 += wA * (float)gA[0] + wB * (float)gB[0];
    a1 += wA * (float)gA[1] + wB * (float)gB[1];
    a2 += wA * (float)gA[2] + wB * (float)gB[2];
    a3 += wA * (float)gA[3] + wB * (float)gB[3];
  }
  a0 += __shfl_xor(a0, 16, 64); a1 += __shfl_xor(a1, 16, 64);
  a2 += __shfl_xor(a2, 16, 64); a3 += __shfl_xor(a3, 16, 64);
  wsum += __shfl_xor(wsum, 16, 64);
  a0 += __shfl_xor(a0, 32, 64); a1 += __shfl_xor(a1, 32, 64);
  a2 += __shfl_xor(a2, 32, 64); a3 += __shfl_xor(a3, 32, 64);
  wsum += __shfl_xor(wsum, 32, 64);
  if (es == 0) {
    float inv = 1.f / wsum;
    float4 bv = *(const float4*)&b[c * 4];
    f32x4 o;
    o[0] = fmaxf(fmaf(a0, inv, bv.x), 0.f);
    o[1] = fmaxf(fmaf(a1, inv, bv.y), 0.f);
    o[2] = fmaxf(fmaf(a2, inv, bv.z), 0.f);
    o[3] = fmaxf(fmaf(a3, inv, bv.w), 0.f);
    __builtin_nontemporal_store(o, (f32x4*)&out[(size_t)node * 64 + c * 4]);
  }
}

extern "C" void kernel_launch(void* const* d_in, const int* in_sizes, int n_in,
                              void* d_out, int out_size, void* d_ws, size_t ws_size,
                              hipStream_t stream) {
  const float* x      = (const float*)d_in[0];
  const int*   ei     = (const int*)d_in[1];
  const float* W1     = (const float*)d_in[2];
  const float* a_src1 = (const float*)d_in[3];
  const float* a_dst1 = (const float*)d_in[4];
  const float* b1     = (const float*)d_in[5];
  const float* W2     = (const float*)d_in[6];
  const float* a_src2 = (const float*)d_in[7];
  const float* a_dst2 = (const float*)d_in[8];
  const float* b2     = (const float*)d_in[9];

  int N = in_sizes[0] / 128;
  int E = in_sizes[1] / 2;
  const int* srcI = ei;
  const int* dstI = ei + E;
  int nb = (N + 255) / 256;
  int nWaves = (N + 15) / 16;
  int nSlots1 = nWaves * 2;  // gemm1: 2 nt-halves per row tile
  int nodeBlocks = (N + 3) / 4;

  char* ws = (char*)d_ws;
  size_t o = 0;
  auto alloc = [&](size_t bytes) -> void* {
    void* p = ws + o;
    o += (bytes + 255) & ~(size_t)255;
    return p;
  };
  f16*   h1f    = (f16*)alloc((size_t)N * 256 * 2);
  f16*   r16    = (f16*)alloc((size_t)N * 256 * 2);
  f16*   h2f    = (f16*)alloc((size_t)N * 64 * 2);
  f16*   Wp1    = (f16*)alloc((size_t)W1_TOT * 2);
  f16*   Wp2    = (f16*)alloc((size_t)W2_TOT * 2);
  float* as1    = (float*)alloc((size_t)N * 8 * 4);  // [node][head]
  float* ad1    = (float*)alloc((size_t)N * 8 * 4);
  float* as2    = (float*)alloc((size_t)N * 4);
  float* ad2    = (float*)alloc((size_t)N * 4);
  int*   offs   = (int*)alloc((size_t)(N + 1) * 4);
  int*   cursor = (int*)alloc((size_t)N * 4);
  int*   col    = (int*)alloc((size_t)E * 4);
  int*   part   = (int*)alloc((size_t)nb * 4);

  // CSR by dst (self-loops implicit in agg kernels)
  hipMemsetAsync(cursor, 0, (size_t)N * 4, stream);
  k_count<<<(E + 255) / 256, 256, 0, stream>>>(dstI, cursor, E);
  k_partial<<<nb, 256, 0, stream>>>(cursor, part, N);
  k_offs<<<nb, 256, 0, stream>>>(cursor, part, offs, N, nb);  // scans partials + zeroes cursor
  k_fill<<<(E + 255) / 256, 256, 0, stream>>>(srcI, dstI, offs, cursor, col, E);

  // weight packs (merged)
  k_packw<<<(W1_TOT + W2_TOT + 255) / 256, 256, 0, stream>>>(
      W1, a_src1, a_dst1, W2, a_src2, a_dst2, Wp1, Wp2);

  // Layer 1
  k_gemm1<<<(nSlots1 + 3) / 4, 256, 0, stream>>>(x, Wp1, h1f, as1, ad1, N, nSlots1);
  k_agg1<<<nodeBlocks, 256, 0, stream>>>(h1f, as1, ad1, offs, col, b1, r16, N);

  // Layer 2
  k_gemm2<<<(nWaves + 3) / 4, 256, 0, stream>>>(r16, Wp2, h2f, as2, ad2, N, nWaves);
  k_agg2<<<nodeBlocks, 256, 0, stream>>>(h2f, as2, ad2, offs, col, b2, (float*)d_out, N);
}

// Round 8
// 220.143 us; speedup vs baseline: 1.8328x; 1.0116x over previous
//
#include <hip/hip_runtime.h>
#include <math.h>

#define NEG_SLOPE 0.2f
__device__ __forceinline__ float leaky(float x) { return fmaxf(x, NEG_SLOPE * x); }

typedef _Float16 f16;
typedef _Float16 f16x2 __attribute__((ext_vector_type(2)));
typedef _Float16 f16x4 __attribute__((ext_vector_type(4)));
typedef _Float16 f16x8 __attribute__((ext_vector_type(8)));
typedef float f32x4 __attribute__((ext_vector_type(4)));

__device__ __forceinline__ int kmap(int lh, int e) {
  return (e < 4) ? lh * 4 + e : 16 + lh * 4 + (e - 4);
}

// ---------------- CSR build ----------------
__global__ void k_count(const int* __restrict__ dst, int* __restrict__ deg, int E) {
  int e = blockIdx.x * blockDim.x + threadIdx.x;
  if (e < E) atomicAdd(&deg[dst[e]], 1);
}

// ---------------- partial-reduce + weight pack (fused, independent work) ----------------
#define W1_TOT (17 * 4 * 64 * 8)
#define W2_TOT (5 * 8 * 64 * 8)
__global__ __launch_bounds__(256) void k_partial_packw(const int* __restrict__ deg,
    int* __restrict__ part, int n, int nb,
    const float* __restrict__ W1, const float* __restrict__ as1f,
    const float* __restrict__ ad1f, const float* __restrict__ W2,
    const float* __restrict__ as2f, const float* __restrict__ ad2f,
    f16* __restrict__ Wp1, f16* __restrict__ Wp2) {
  if ((int)blockIdx.x < nb) {
    __shared__ int s[256];
    int i = blockIdx.x * 256 + threadIdx.x;
    s[threadIdx.x] = (i < n) ? deg[i] : 0;
    __syncthreads();
    for (int off = 128; off > 0; off >>= 1) {
      if (threadIdx.x < off) s[threadIdx.x] += s[threadIdx.x + off];
      __syncthreads();
    }
    if (threadIdx.x == 0) part[blockIdx.x] = s[0];
  }
  int tid = blockIdx.x * 256 + threadIdx.x;
  if (tid < W1_TOT) {
    int e = tid & 7, l = (tid >> 3) & 63, ks = (tid >> 9) & 3, nt = tid >> 11;
    int lh = l >> 4, li = l & 15;
    int k = ks * 32 + kmap(lh, e);
    float v;
    if (nt < 16) {
      v = W1[k * 256 + nt * 16 + li];
    } else {
      int h = li & 7;
      const float* a = (li < 8) ? (as1f + h * 32) : (ad1f + h * 32);
      v = 0.f;
      for (int j = 0; j < 32; ++j) v += W1[k * 256 + h * 32 + j] * a[j];
    }
    Wp1[tid] = (f16)v;
  } else if (tid < W1_TOT + W2_TOT) {
    int t2 = tid - W1_TOT;
    int e = t2 & 7, l = (t2 >> 3) & 63, ks = (t2 >> 9) & 7, nt = t2 >> 12;
    int lh = l >> 4, li = l & 15;
    int k = ks * 32 + kmap(lh, e);
    float v = 0.f;
    if (nt < 4) {
      v = W2[k * 64 + nt * 16 + li];
    } else if (li == 0) {
      for (int j = 0; j < 64; ++j) v += W2[k * 64 + j] * as2f[j];
    } else if (li == 1) {
      for (int j = 0; j < 64; ++j) v += W2[k * 64 + j] * ad2f[j];
    }
    Wp2[t2] = (f16)v;
  }
}

// scans partials redundantly per block (nb<=256), then block-local exclusive scan.
// also zeroes deg (cursor) for the fill pass.
__global__ __launch_bounds__(256) void k_offs(int* __restrict__ deg,
                                              const int* __restrict__ part,
                                              int* __restrict__ offs, int n, int nb) {
  __shared__ int ps[256];
  __shared__ int s[256];
  int t = threadIdx.x;
  ps[t] = (t < nb) ? part[t] : 0;
  __syncthreads();
  for (int off = 1; off < 256; off <<= 1) {
    int u = (t >= off) ? ps[t - off] : 0;
    __syncthreads();
    ps[t] += u;
    __syncthreads();
  }
  int base = (blockIdx.x > 0) ? ps[blockIdx.x - 1] : 0;

  int i = blockIdx.x * 256 + t;
  int v = (i < n) ? deg[i] : 0;
  s[t] = v;
  __syncthreads();
  for (int off = 1; off < 256; off <<= 1) {
    int u = (t >= off) ? s[t - off] : 0;
    __syncthreads();
    s[t] += u;
    __syncthreads();
  }
  int excl = base + s[t] - v;
  if (i < n) {
    offs[i] = excl;
    deg[i] = 0;  // reset cursor for k_fill
  }
  if (i == n - 1) offs[n] = excl + v;
}

__global__ void k_fill(const int* __restrict__ src, const int* __restrict__ dst,
                       const int* __restrict__ offs, int* __restrict__ cursor,
                       int* __restrict__ col, int E) {
  int e = blockIdx.x * blockDim.x + threadIdx.x;
  if (e >= E) return;
  int d = dst[e];
  int pos = atomicAdd(&cursor[d], 1);
  col[offs[d] + pos] = src[e];
}

// ---------------- MFMA GEMM1: [N,128]@[128,256], fp32 X in-reg cvt, fused alpha ----------------
// 2 waves per 16-row tile: half0 -> nt 0..7, half1 -> nt 8..16 (incl alpha tile)
__global__ __launch_bounds__(256) void k_gemm1(const float* __restrict__ x,
    const f16* __restrict__ Wp1, f16* __restrict__ h16,
    float* __restrict__ as, float* __restrict__ ad, int n, int nSlots) {
  int slot = blockIdx.x * 4 + (threadIdx.x >> 6);
  if (slot >= nSlots) return;
  int half = slot & 1;
  int wid = slot >> 1;
  int lane = threadIdx.x & 63, lh = lane >> 4, li = lane & 15;
  size_t arow = (size_t)min(wid * 16 + li, n - 1);
  f16x8 a[4];
#pragma unroll
  for (int ks = 0; ks < 4; ++ks) {
    float4 lo = *(const float4*)&x[arow * 128 + ks * 32 + lh * 4];
    float4 hi = *(const float4*)&x[arow * 128 + ks * 32 + 16 + lh * 4];
    a[ks][0] = (f16)lo.x; a[ks][1] = (f16)lo.y; a[ks][2] = (f16)lo.z; a[ks][3] = (f16)lo.w;
    a[ks][4] = (f16)hi.x; a[ks][5] = (f16)hi.y; a[ks][6] = (f16)hi.z; a[ks][7] = (f16)hi.w;
  }
  int rbase = wid * 16 + lh * 4;
  int ntBeg = half ? 8 : 0;
  int ntEnd = half ? 17 : 8;
  for (int nt = ntBeg; nt < ntEnd; ++nt) {
    f32x4 acc = {0.f, 0.f, 0.f, 0.f};
#pragma unroll
    for (int ks = 0; ks < 4; ++ks) {
      f16x8 b = *(const f16x8*)&Wp1[((nt * 4 + ks) * 64 + lane) * 8];
      acc = __builtin_amdgcn_mfma_f32_16x16x32_f16(a[ks], b, acc, 0, 0, 0);
    }
    if (nt < 16) {
#pragma unroll
      for (int r = 0; r < 4; ++r) {
        int rr = rbase + r;
        if (rr < n) h16[(size_t)rr * 256 + nt * 16 + li] = (f16)acc[r];
      }
    } else {
#pragma unroll
      for (int r = 0; r < 4; ++r) {
        int rr = rbase + r;
        if (rr < n) {
          if (li < 8) as[(size_t)rr * 8 + li] = acc[r];
          else        ad[(size_t)rr * 8 + (li - 8)] = acc[r];
        }
      }
    }
  }
}

// ---------------- MFMA GEMM2: [N,256]@[256,64] + fused alpha ----------------
__global__ __launch_bounds__(256) void k_gemm2(const f16* __restrict__ R16,
    const f16* __restrict__ Wp2, f16* __restrict__ h2,
    float* __restrict__ as, float* __restrict__ ad, int n, int nWaves) {
  int wid = blockIdx.x * 4 + (threadIdx.x >> 6);
  if (wid >= nWaves) return;
  int lane = threadIdx.x & 63, lh = lane >> 4, li = lane & 15;
  size_t arow = (size_t)min(wid * 16 + li, n - 1);
  f16x8 a[8];
#pragma unroll
  for (int ks = 0; ks < 8; ++ks) {
    f16x4 lo = *(const f16x4*)&R16[arow * 256 + ks * 32 + lh * 4];
    f16x4 hi = *(const f16x4*)&R16[arow * 256 + ks * 32 + 16 + lh * 4];
    a[ks][0] = lo[0]; a[ks][1] = lo[1]; a[ks][2] = lo[2]; a[ks][3] = lo[3];
    a[ks][4] = hi[0]; a[ks][5] = hi[1]; a[ks][6] = hi[2]; a[ks][7] = hi[3];
  }
  int rbase = wid * 16 + lh * 4;
#pragma unroll
  for (int nt = 0; nt < 5; ++nt) {
    f32x4 acc = {0.f, 0.f, 0.f, 0.f};
#pragma unroll
    for (int ks = 0; ks < 8; ++ks) {
      f16x8 b = *(const f16x8*)&Wp2[((nt * 8 + ks) * 64 + lane) * 8];
      acc = __builtin_amdgcn_mfma_f32_16x16x32_f16(a[ks], b, acc, 0, 0, 0);
    }
    if (nt < 4) {
#pragma unroll
      for (int r = 0; r < 4; ++r) {
        int rr = rbase + r;
        if (rr < n) h2[(size_t)rr * 64 + nt * 16 + li] = (f16)acc[r];
      }
    } else {
#pragma unroll
      for (int r = 0; r < 4; ++r) {
        int rr = rbase + r;
        if (rr < n) {
          if (li == 0) as[rr] = acc[r];
          else if (li == 1) ad[rr] = acc[r];
        }
      }
    }
  }
}

// ---------------- Layer 1 aggregation: wave/node, 16 edges in flight (padded) ----------------
#define DEPTH1 16
__global__ __launch_bounds__(256) void k_agg1(const f16* __restrict__ h16,
    const float* __restrict__ as, const float* __restrict__ ad,
    const int* __restrict__ offs, const int* __restrict__ col,
    const float* __restrict__ b, f16* __restrict__ out, int n) {
  int node = blockIdx.x * 4 + (threadIdx.x >> 6);
  if (node >= n) return;
  node = __builtin_amdgcn_readfirstlane(node);
  int lane = threadIdx.x & 63;
  int head = lane >> 3;
  int c0 = lane * 4;
  int beg = offs[node], end = offs[node + 1];
  float adn = ad[node * 8 + head];

  float denom, ax, ay, az, aw;
  {  // self-loop
    float w = __expf(leaky(as[node * 8 + head] + adn));
    f16x4 g = *(const f16x4*)&h16[(size_t)node * 256 + c0];
    denom = w;
    ax = w * (float)g[0]; ay = w * (float)g[1];
    az = w * (float)g[2]; aw = w * (float)g[3];
  }
  for (int p = beg; p < end; p += DEPTH1) {
    int cnt = end - p;  // >0
    int s[DEPTH1];
#pragma unroll
    for (int j = 0; j < DEPTH1; ++j) s[j] = (j < cnt) ? col[p + j] : node;
    float e[DEPTH1];
#pragma unroll
    for (int j = 0; j < DEPTH1; ++j) e[j] = as[s[j] * 8 + head];
    f16x4 g[DEPTH1];
#pragma unroll
    for (int j = 0; j < DEPTH1; ++j) g[j] = *(const f16x4*)&h16[(size_t)s[j] * 256 + c0];
    float w[DEPTH1];
#pragma unroll
    for (int j = 0; j < DEPTH1; ++j) w[j] = (j < cnt) ? __expf(leaky(e[j] + adn)) : 0.f;
#pragma unroll
    for (int j = 0; j < DEPTH1; ++j) {
      denom += w[j];
      ax += w[j] * (float)g[j][0]; ay += w[j] * (float)g[j][1];
      az += w[j] * (float)g[j][2]; aw += w[j] * (float)g[j][3];
    }
  }
  float inv = 1.f / denom;
  float4 bv = *(const float4*)&b[c0];
  f16x4 o;
  o[0] = (f16)fmaxf(fmaf(ax, inv, bv.x), 0.f);
  o[1] = (f16)fmaxf(fmaf(ay, inv, bv.y), 0.f);
  o[2] = (f16)fmaxf(fmaf(az, inv, bv.z), 0.f);
  o[3] = (f16)fmaxf(fmaf(aw, inv, bv.w), 0.f);
  __builtin_nontemporal_store(o, (f16x4*)&out[(size_t)node * 256 + c0]);
}

// ---------------- Layer 2 aggregation: wave/node, 4 slots x 4 chains = 16 in flight ----------------
__global__ __launch_bounds__(256) void k_agg2(const f16* __restrict__ h2,
    const float* __restrict__ as, const float* __restrict__ ad,
    const int* __restrict__ offs, const int* __restrict__ col,
    const float* __restrict__ b, float* __restrict__ out, int n) {
  int node = blockIdx.x * 4 + (threadIdx.x >> 6);
  if (node >= n) return;
  node = __builtin_amdgcn_readfirstlane(node);
  int lane = threadIdx.x & 63;
  int es = lane >> 4;   // edge slot 0..3
  int c = lane & 15;    // channel quad: ch = c*4
  int beg = offs[node], end = offs[node + 1];
  int deg = end - beg;
  float adn = ad[node];

  float a0 = 0.f, a1 = 0.f, a2 = 0.f, a3 = 0.f, wsum = 0.f;
  if (es == 0) {  // self-loop once
    float w = __expf(leaky(as[node] + adn));
    f16x4 g = *(const f16x4*)&h2[(size_t)node * 64 + c * 4];
    wsum = w;
    a0 = w * (float)g[0]; a1 = w * (float)g[1];
    a2 = w * (float)g[2]; a3 = w * (float)g[3];
  }
  for (int base = 0; base < deg; base += 16) {
    int s[4]; float e[4]; f16x4 g[4]; float w[4];
#pragma unroll
    for (int q = 0; q < 4; ++q) {
      int idx = base + q * 4 + es;
      s[q] = (idx < deg) ? col[beg + idx] : node;
    }
#pragma unroll
    for (int q = 0; q < 4; ++q) e[q] = as[s[q]];
#pragma unroll
    for (int q = 0; q < 4; ++q) g[q] = *(const f16x4*)&h2[(size_t)s[q] * 64 + c * 4];
#pragma unroll
    for (int q = 0; q < 4; ++q) {
      int idx = base + q * 4 + es;
      w[q] = (idx < deg) ? __expf(leaky(e[q] + adn)) : 0.f;
    }
#pragma unroll
    for (int q = 0; q < 4; ++q) {
      wsum += w[q];
      a0 += w[q] * (float)g[q][0]; a1 += w[q] * (float)g[q][1];
      a2 += w[q] * (float)g[q][2]; a3 += w[q] * (float)g[q][3];
    }
  }
  a0 += __shfl_xor(a0, 16, 64); a1 += __shfl_xor(a1, 16, 64);
  a2 += __shfl_xor(a2, 16, 64); a3 += __shfl_xor(a3, 16, 64);
  wsum += __shfl_xor(wsum, 16, 64);
  a0 += __shfl_xor(a0, 32, 64); a1 += __shfl_xor(a1, 32, 64);
  a2 += __shfl_xor(a2, 32, 64); a3 += __shfl_xor(a3, 32, 64);
  wsum += __shfl_xor(wsum, 32, 64);
  if (es == 0) {
    float inv = 1.f / wsum;
    float4 bv = *(const float4*)&b[c * 4];
    f32x4 o;
    o[0] = fmaxf(fmaf(a0, inv, bv.x), 0.f);
    o[1] = fmaxf(fmaf(a1, inv, bv.y), 0.f);
    o[2] = fmaxf(fmaf(a2, inv, bv.z), 0.f);
    o[3] = fmaxf(fmaf(a3, inv, bv.w), 0.f);
    __builtin_nontemporal_store(o, (f32x4*)&out[(size_t)node * 64 + c * 4]);
  }
}

extern "C" void kernel_launch(void* const* d_in, const int* in_sizes, int n_in,
                              void* d_out, int out_size, void* d_ws, size_t ws_size,
                              hipStream_t stream) {
  const float* x      = (const float*)d_in[0];
  const int*   ei     = (const int*)d_in[1];
  const float* W1     = (const float*)d_in[2];
  const float* a_src1 = (const float*)d_in[3];
  const float* a_dst1 = (const float*)d_in[4];
  const float* b1     = (const float*)d_in[5];
  const float* W2     = (const float*)d_in[6];
  const float* a_src2 = (const float*)d_in[7];
  const float* a_dst2 = (const float*)d_in[8];
  const float* b2     = (const float*)d_in[9];

  int N = in_sizes[0] / 128;
  int E = in_sizes[1] / 2;
  const int* srcI = ei;
  const int* dstI = ei + E;
  int nb = (N + 255) / 256;
  int packBlocks = (W1_TOT + W2_TOT + 255) / 256;
  int ppBlocks = nb > packBlocks ? nb : packBlocks;
  int nWaves = (N + 15) / 16;
  int nSlots1 = nWaves * 2;  // gemm1: 2 nt-halves per row tile
  int nodeBlocks = (N + 3) / 4;

  char* ws = (char*)d_ws;
  size_t o = 0;
  auto alloc = [&](size_t bytes) -> void* {
    void* p = ws + o;
    o += (bytes + 255) & ~(size_t)255;
    return p;
  };
  f16*   h1f    = (f16*)alloc((size_t)N * 256 * 2);
  f16*   r16    = (f16*)alloc((size_t)N * 256 * 2);
  f16*   h2f    = (f16*)alloc((size_t)N * 64 * 2);
  f16*   Wp1    = (f16*)alloc((size_t)W1_TOT * 2);
  f16*   Wp2    = (f16*)alloc((size_t)W2_TOT * 2);
  float* as1    = (float*)alloc((size_t)N * 8 * 4);  // [node][head]
  float* ad1    = (float*)alloc((size_t)N * 8 * 4);
  float* as2    = (float*)alloc((size_t)N * 4);
  float* ad2    = (float*)alloc((size_t)N * 4);
  int*   offs   = (int*)alloc((size_t)(N + 1) * 4);
  int*   cursor = (int*)alloc((size_t)N * 4);
  int*   col    = (int*)alloc((size_t)E * 4);
  int*   part   = (int*)alloc((size_t)nb * 4);

  // CSR by dst (self-loops implicit in agg kernels) + weight pack fused in
  hipMemsetAsync(cursor, 0, (size_t)N * 4, stream);
  k_count<<<(E + 255) / 256, 256, 0, stream>>>(dstI, cursor, E);
  k_partial_packw<<<ppBlocks, 256, 0, stream>>>(cursor, part, N, nb,
      W1, a_src1, a_dst1, W2, a_src2, a_dst2, Wp1, Wp2);
  k_offs<<<nb, 256, 0, stream>>>(cursor, part, offs, N, nb);  // scans partials + zeroes cursor
  k_fill<<<(E + 255) / 256, 256, 0, stream>>>(srcI, dstI, offs, cursor, col, E);

  // Layer 1
  k_gemm1<<<(nSlots1 + 3) / 4, 256, 0, stream>>>(x, Wp1, h1f, as1, ad1, N, nSlots1);
  k_agg1<<<nodeBlocks, 256, 0, stream>>>(h1f, as1, ad1, offs, col, b1, r16, N);

  // Layer 2
  k_gemm2<<<(nWaves + 3) / 4, 256, 0, stream>>>(r16, Wp2, h2f, as2, ad2, N, nWaves);
  k_agg2<<<nodeBlocks, 256, 0, stream>>>(h2f, as2, ad2, offs, col, b2, (float*)d_out, N);
}

// Round 9
// 215.987 us; speedup vs baseline: 1.8680x; 1.0192x over previous
//
#include <hip/hip_runtime.h>
#include <math.h>

#define NEG_SLOPE 0.2f
__device__ __forceinline__ float leaky(float x) { return fmaxf(x, NEG_SLOPE * x); }

typedef _Float16 f16;
typedef _Float16 f16x2 __attribute__((ext_vector_type(2)));
typedef _Float16 f16x4 __attribute__((ext_vector_type(4)));
typedef _Float16 f16x8 __attribute__((ext_vector_type(8)));
typedef float f32x4 __attribute__((ext_vector_type(4)));

__device__ __forceinline__ int kmap(int lh, int e) {
  return (e < 4) ? lh * 4 + e : 16 + lh * 4 + (e - 4);
}

// ---------------- CSR build ----------------
__global__ void k_count(const int* __restrict__ dst, int* __restrict__ deg, int E) {
  int e = blockIdx.x * blockDim.x + threadIdx.x;
  if (e < E) atomicAdd(&deg[dst[e]], 1);
}

// ---------------- partial-reduce + weight pack (fused, independent work) ----------------
#define W1_TOT (17 * 4 * 64 * 8)
#define W2_TOT (5 * 8 * 64 * 8)
__global__ __launch_bounds__(256) void k_partial_packw(const int* __restrict__ deg,
    int* __restrict__ part, int n, int nb,
    const float* __restrict__ W1, const float* __restrict__ as1f,
    const float* __restrict__ ad1f, const float* __restrict__ W2,
    const float* __restrict__ as2f, const float* __restrict__ ad2f,
    f16* __restrict__ Wp1, f16* __restrict__ Wp2) {
  if ((int)blockIdx.x < nb) {
    __shared__ int s[256];
    int i = blockIdx.x * 256 + threadIdx.x;
    s[threadIdx.x] = (i < n) ? deg[i] : 0;
    __syncthreads();
    for (int off = 128; off > 0; off >>= 1) {
      if (threadIdx.x < off) s[threadIdx.x] += s[threadIdx.x + off];
      __syncthreads();
    }
    if (threadIdx.x == 0) part[blockIdx.x] = s[0];
  }
  int tid = blockIdx.x * 256 + threadIdx.x;
  if (tid < W1_TOT) {
    int e = tid & 7, l = (tid >> 3) & 63, ks = (tid >> 9) & 3, nt = tid >> 11;
    int lh = l >> 4, li = l & 15;
    int k = ks * 32 + kmap(lh, e);
    float v;
    if (nt < 16) {
      v = W1[k * 256 + nt * 16 + li];
    } else {
      int h = li & 7;
      const float* a = (li < 8) ? (as1f + h * 32) : (ad1f + h * 32);
      v = 0.f;
      for (int j = 0; j < 32; ++j) v += W1[k * 256 + h * 32 + j] * a[j];
    }
    Wp1[tid] = (f16)v;
  } else if (tid < W1_TOT + W2_TOT) {
    int t2 = tid - W1_TOT;
    int e = t2 & 7, l = (t2 >> 3) & 63, ks = (t2 >> 9) & 7, nt = t2 >> 12;
    int lh = l >> 4, li = l & 15;
    int k = ks * 32 + kmap(lh, e);
    float v = 0.f;
    if (nt < 4) {
      v = W2[k * 64 + nt * 16 + li];
    } else if (li == 0) {
      for (int j = 0; j < 64; ++j) v += W2[k * 64 + j] * as2f[j];
    } else if (li == 1) {
      for (int j = 0; j < 64; ++j) v += W2[k * 64 + j] * ad2f[j];
    }
    Wp2[t2] = (f16)v;
  }
}

// scans partials redundantly per block (nb<=256), then block-local exclusive scan.
// also zeroes deg (cursor) for the fill pass.
__global__ __launch_bounds__(256) void k_offs(int* __restrict__ deg,
                                              const int* __restrict__ part,
                                              int* __restrict__ offs, int n, int nb) {
  __shared__ int ps[256];
  __shared__ int s[256];
  int t = threadIdx.x;
  ps[t] = (t < nb) ? part[t] : 0;
  __syncthreads();
  for (int off = 1; off < 256; off <<= 1) {
    int u = (t >= off) ? ps[t - off] : 0;
    __syncthreads();
    ps[t] += u;
    __syncthreads();
  }
  int base = (blockIdx.x > 0) ? ps[blockIdx.x - 1] : 0;

  int i = blockIdx.x * 256 + t;
  int v = (i < n) ? deg[i] : 0;
  s[t] = v;
  __syncthreads();
  for (int off = 1; off < 256; off <<= 1) {
    int u = (t >= off) ? s[t - off] : 0;
    __syncthreads();
    s[t] += u;
    __syncthreads();
  }
  int excl = base + s[t] - v;
  if (i < n) {
    offs[i] = excl;
    deg[i] = 0;  // reset cursor for k_fill
  }
  if (i == n - 1) offs[n] = excl + v;
}

// ---------------- fused: CSR fill (blocks < fillBlocks) | MFMA GEMM1 (rest) ----------------
// fill: random 4B scatter; gemm1: [N,128]@[128,256] fp16 MFMA + fused alpha tile.
// Independent work -> run concurrently in one dispatch.
__global__ __launch_bounds__(256) void k_fill_gemm1(
    const int* __restrict__ src, const int* __restrict__ dst,
    const int* __restrict__ offs, int* __restrict__ cursor,
    int* __restrict__ col, int E, int fillBlocks,
    const float* __restrict__ x, const f16* __restrict__ Wp1,
    f16* __restrict__ h16, float* __restrict__ as, float* __restrict__ ad,
    int n, int nSlots) {
  if ((int)blockIdx.x < fillBlocks) {
    int e = blockIdx.x * 256 + threadIdx.x;
    if (e >= E) return;
    int d = dst[e];
    int pos = atomicAdd(&cursor[d], 1);
    col[offs[d] + pos] = src[e];
    return;
  }
  int slot = (blockIdx.x - fillBlocks) * 4 + (threadIdx.x >> 6);
  if (slot >= nSlots) return;
  int half = slot & 1;
  int wid = slot >> 1;
  int lane = threadIdx.x & 63, lh = lane >> 4, li = lane & 15;
  size_t arow = (size_t)min(wid * 16 + li, n - 1);
  f16x8 a[4];
#pragma unroll
  for (int ks = 0; ks < 4; ++ks) {
    float4 lo = *(const float4*)&x[arow * 128 + ks * 32 + lh * 4];
    float4 hi = *(const float4*)&x[arow * 128 + ks * 32 + 16 + lh * 4];
    a[ks][0] = (f16)lo.x; a[ks][1] = (f16)lo.y; a[ks][2] = (f16)lo.z; a[ks][3] = (f16)lo.w;
    a[ks][4] = (f16)hi.x; a[ks][5] = (f16)hi.y; a[ks][6] = (f16)hi.z; a[ks][7] = (f16)hi.w;
  }
  int rbase = wid * 16 + lh * 4;
  int ntBeg = half ? 8 : 0;
  int ntEnd = half ? 17 : 8;
  for (int nt = ntBeg; nt < ntEnd; ++nt) {
    f32x4 acc = {0.f, 0.f, 0.f, 0.f};
#pragma unroll
    for (int ks = 0; ks < 4; ++ks) {
      f16x8 b = *(const f16x8*)&Wp1[((nt * 4 + ks) * 64 + lane) * 8];
      acc = __builtin_amdgcn_mfma_f32_16x16x32_f16(a[ks], b, acc, 0, 0, 0);
    }
    if (nt < 16) {
#pragma unroll
      for (int r = 0; r < 4; ++r) {
        int rr = rbase + r;
        if (rr < n) h16[(size_t)rr * 256 + nt * 16 + li] = (f16)acc[r];
      }
    } else {
#pragma unroll
      for (int r = 0; r < 4; ++r) {
        int rr = rbase + r;
        if (rr < n) {
          if (li < 8) as[(size_t)rr * 8 + li] = acc[r];
          else        ad[(size_t)rr * 8 + (li - 8)] = acc[r];
        }
      }
    }
  }
}

// ---------------- MFMA GEMM2: [N,256]@[256,64] + fused alpha ----------------
__global__ __launch_bounds__(256) void k_gemm2(const f16* __restrict__ R16,
    const f16* __restrict__ Wp2, f16* __restrict__ h2,
    float* __restrict__ as, float* __restrict__ ad, int n, int nWaves) {
  int wid = blockIdx.x * 4 + (threadIdx.x >> 6);
  if (wid >= nWaves) return;
  int lane = threadIdx.x & 63, lh = lane >> 4, li = lane & 15;
  size_t arow = (size_t)min(wid * 16 + li, n - 1);
  f16x8 a[8];
#pragma unroll
  for (int ks = 0; ks < 8; ++ks) {
    f16x4 lo = *(const f16x4*)&R16[arow * 256 + ks * 32 + lh * 4];
    f16x4 hi = *(const f16x4*)&R16[arow * 256 + ks * 32 + 16 + lh * 4];
    a[ks][0] = lo[0]; a[ks][1] = lo[1]; a[ks][2] = lo[2]; a[ks][3] = lo[3];
    a[ks][4] = hi[0]; a[ks][5] = hi[1]; a[ks][6] = hi[2]; a[ks][7] = hi[3];
  }
  int rbase = wid * 16 + lh * 4;
#pragma unroll
  for (int nt = 0; nt < 5; ++nt) {
    f32x4 acc = {0.f, 0.f, 0.f, 0.f};
#pragma unroll
    for (int ks = 0; ks < 8; ++ks) {
      f16x8 b = *(const f16x8*)&Wp2[((nt * 8 + ks) * 64 + lane) * 8];
      acc = __builtin_amdgcn_mfma_f32_16x16x32_f16(a[ks], b, acc, 0, 0, 0);
    }
    if (nt < 4) {
#pragma unroll
      for (int r = 0; r < 4; ++r) {
        int rr = rbase + r;
        if (rr < n) h2[(size_t)rr * 64 + nt * 16 + li] = (f16)acc[r];
      }
    } else {
#pragma unroll
      for (int r = 0; r < 4; ++r) {
        int rr = rbase + r;
        if (rr < n) {
          if (li == 0) as[rr] = acc[r];
          else if (li == 1) ad[rr] = acc[r];
        }
      }
    }
  }
}

// ---------------- Layer 1 aggregation: wave/node, 8 edges in flight (R7 form) ----------------
__global__ __launch_bounds__(256) void k_agg1(const f16* __restrict__ h16,
    const float* __restrict__ as, const float* __restrict__ ad,
    const int* __restrict__ offs, const int* __restrict__ col,
    const float* __restrict__ b, f16* __restrict__ out, int n) {
  int node = blockIdx.x * 4 + (threadIdx.x >> 6);
  if (node >= n) return;
  node = __builtin_amdgcn_readfirstlane(node);
  int lane = threadIdx.x & 63;
  int head = lane >> 3;
  int c0 = lane * 4;
  int beg = offs[node], end = offs[node + 1];
  float adn = ad[node * 8 + head];

  float denom, ax, ay, az, aw;
  {  // self-loop
    float w = __expf(leaky(as[node * 8 + head] + adn));
    f16x4 g = *(const f16x4*)&h16[(size_t)node * 256 + c0];
    denom = w;
    ax = w * (float)g[0]; ay = w * (float)g[1];
    az = w * (float)g[2]; aw = w * (float)g[3];
  }
  int p = beg;
  for (; p + 8 <= end; p += 8) {
    int s[8];
#pragma unroll
    for (int j = 0; j < 8; ++j) s[j] = col[p + j];  // uniform -> s_load
    float e[8];
#pragma unroll
    for (int j = 0; j < 8; ++j) e[j] = as[s[j] * 8 + head];
    f16x4 g[8];
#pragma unroll
    for (int j = 0; j < 8; ++j) g[j] = *(const f16x4*)&h16[(size_t)s[j] * 256 + c0];
    float w[8];
#pragma unroll
    for (int j = 0; j < 8; ++j) w[j] = __expf(leaky(e[j] + adn));
#pragma unroll
    for (int j = 0; j < 8; ++j) {
      denom += w[j];
      ax += w[j] * (float)g[j][0]; ay += w[j] * (float)g[j][1];
      az += w[j] * (float)g[j][2]; aw += w[j] * (float)g[j][3];
    }
  }
  for (; p < end; ++p) {
    int s = col[p];
    float w = __expf(leaky(as[s * 8 + head] + adn));
    f16x4 g = *(const f16x4*)&h16[(size_t)s * 256 + c0];
    denom += w;
    ax += w * (float)g[0]; ay += w * (float)g[1];
    az += w * (float)g[2]; aw += w * (float)g[3];
  }
  float inv = 1.f / denom;
  float4 bv = *(const float4*)&b[c0];
  f16x4 o;
  o[0] = (f16)fmaxf(fmaf(ax, inv, bv.x), 0.f);
  o[1] = (f16)fmaxf(fmaf(ay, inv, bv.y), 0.f);
  o[2] = (f16)fmaxf(fmaf(az, inv, bv.z), 0.f);
  o[3] = (f16)fmaxf(fmaf(aw, inv, bv.w), 0.f);
  __builtin_nontemporal_store(o, (f16x4*)&out[(size_t)node * 256 + c0]);
}

// ---------------- Layer 2 aggregation: wave/node, 4 slots x 4 chains = 16 in flight ----------------
__global__ __launch_bounds__(256) void k_agg2(const f16* __restrict__ h2,
    const float* __restrict__ as, const float* __restrict__ ad,
    const int* __restrict__ offs, const int* __restrict__ col,
    const float* __restrict__ b, float* __restrict__ out, int n) {
  int node = blockIdx.x * 4 + (threadIdx.x >> 6);
  if (node >= n) return;
  node = __builtin_amdgcn_readfirstlane(node);
  int lane = threadIdx.x & 63;
  int es = lane >> 4;   // edge slot 0..3
  int c = lane & 15;    // channel quad: ch = c*4
  int beg = offs[node], end = offs[node + 1];
  int deg = end - beg;
  float adn = ad[node];

  float a0 = 0.f, a1 = 0.f, a2 = 0.f, a3 = 0.f, wsum = 0.f;
  if (es == 0) {  // self-loop once
    float w = __expf(leaky(as[node] + adn));
    f16x4 g = *(const f16x4*)&h2[(size_t)node * 64 + c * 4];
    wsum = w;
    a0 = w * (float)g[0]; a1 = w * (float)g[1];
    a2 = w * (float)g[2]; a3 = w * (float)g[3];
  }
  for (int base = 0; base < deg; base += 16) {
    int s[4]; float e[4]; f16x4 g[4]; float w[4];
#pragma unroll
    for (int q = 0; q < 4; ++q) {
      int idx = base + q * 4 + es;
      s[q] = (idx < deg) ? col[beg + idx] : node;
    }
#pragma unroll
    for (int q = 0; q < 4; ++q) e[q] = as[s[q]];
#pragma unroll
    for (int q = 0; q < 4; ++q) g[q] = *(const f16x4*)&h2[(size_t)s[q] * 64 + c * 4];
#pragma unroll
    for (int q = 0; q < 4; ++q) {
      int idx = base + q * 4 + es;
      w[q] = (idx < deg) ? __expf(leaky(e[q] + adn)) : 0.f;
    }
#pragma unroll
    for (int q = 0; q < 4; ++q) {
      wsum += w[q];
      a0 += w[q] * (float)g[q][0]; a1 += w[q] * (float)g[q][1];
      a2 += w[q] * (float)g[q][2]; a3 += w[q] * (float)g[q][3];
    }
  }
  a0 += __shfl_xor(a0, 16, 64); a1 += __shfl_xor(a1, 16, 64);
  a2 += __shfl_xor(a2, 16, 64); a3 += __shfl_xor(a3, 16, 64);
  wsum += __shfl_xor(wsum, 16, 64);
  a0 += __shfl_xor(a0, 32, 64); a1 += __shfl_xor(a1, 32, 64);
  a2 += __shfl_xor(a2, 32, 64); a3 += __shfl_xor(a3, 32, 64);
  wsum += __shfl_xor(wsum, 32, 64);
  if (es == 0) {
    float inv = 1.f / wsum;
    float4 bv = *(const float4*)&b[c * 4];
    f32x4 o;
    o[0] = fmaxf(fmaf(a0, inv, bv.x), 0.f);
    o[1] = fmaxf(fmaf(a1, inv, bv.y), 0.f);
    o[2] = fmaxf(fmaf(a2, inv, bv.z), 0.f);
    o[3] = fmaxf(fmaf(a3, inv, bv.w), 0.f);
    __builtin_nontemporal_store(o, (f32x4*)&out[(size_t)node * 64 + c * 4]);
  }
}

extern "C" void kernel_launch(void* const* d_in, const int* in_sizes, int n_in,
                              void* d_out, int out_size, void* d_ws, size_t ws_size,
                              hipStream_t stream) {
  const float* x      = (const float*)d_in[0];
  const int*   ei     = (const int*)d_in[1];
  const float* W1     = (const float*)d_in[2];
  const float* a_src1 = (const float*)d_in[3];
  const float* a_dst1 = (const float*)d_in[4];
  const float* b1     = (const float*)d_in[5];
  const float* W2     = (const float*)d_in[6];
  const float* a_src2 = (const float*)d_in[7];
  const float* a_dst2 = (const float*)d_in[8];
  const float* b2     = (const float*)d_in[9];

  int N = in_sizes[0] / 128;
  int E = in_sizes[1] / 2;
  const int* srcI = ei;
  const int* dstI = ei + E;
  int nb = (N + 255) / 256;
  int packBlocks = (W1_TOT + W2_TOT + 255) / 256;
  int ppBlocks = nb > packBlocks ? nb : packBlocks;
  int nWaves = (N + 15) / 16;
  int nSlots1 = nWaves * 2;  // gemm1: 2 nt-halves per row tile
  int fillBlocks = (E + 255) / 256;
  int gemm1Blocks = (nSlots1 + 3) / 4;
  int nodeBlocks = (N + 3) / 4;

  char* ws = (char*)d_ws;
  size_t o = 0;
  auto alloc = [&](size_t bytes) -> void* {
    void* p = ws + o;
    o += (bytes + 255) & ~(size_t)255;
    return p;
  };
  f16*   h1f    = (f16*)alloc((size_t)N * 256 * 2);
  f16*   r16    = (f16*)alloc((size_t)N * 256 * 2);
  f16*   h2f    = (f16*)alloc((size_t)N * 64 * 2);
  f16*   Wp1    = (f16*)alloc((size_t)W1_TOT * 2);
  f16*   Wp2    = (f16*)alloc((size_t)W2_TOT * 2);
  float* as1    = (float*)alloc((size_t)N * 8 * 4);  // [node][head]
  float* ad1    = (float*)alloc((size_t)N * 8 * 4);
  float* as2    = (float*)alloc((size_t)N * 4);
  float* ad2    = (float*)alloc((size_t)N * 4);
  int*   offs   = (int*)alloc((size_t)(N + 1) * 4);
  int*   cursor = (int*)alloc((size_t)N * 4);
  int*   col    = (int*)alloc((size_t)E * 4);
  int*   part   = (int*)alloc((size_t)nb * 4);

  // CSR by dst (self-loops implicit in agg kernels) + weight pack fused in
  hipMemsetAsync(cursor, 0, (size_t)N * 4, stream);
  k_count<<<(E + 255) / 256, 256, 0, stream>>>(dstI, cursor, E);
  k_partial_packw<<<ppBlocks, 256, 0, stream>>>(cursor, part, N, nb,
      W1, a_src1, a_dst1, W2, a_src2, a_dst2, Wp1, Wp2);
  k_offs<<<nb, 256, 0, stream>>>(cursor, part, offs, N, nb);  // scans partials + zeroes cursor

  // fused: CSR fill || Layer-1 GEMM (independent)
  k_fill_gemm1<<<fillBlocks + gemm1Blocks, 256, 0, stream>>>(
      srcI, dstI, offs, cursor, col, E, fillBlocks,
      x, Wp1, h1f, as1, ad1, N, nSlots1);

  // Layer 1 aggregation
  k_agg1<<<nodeBlocks, 256, 0, stream>>>(h1f, as1, ad1, offs, col, b1, r16, N);

  // Layer 2
  k_gemm2<<<(nWaves + 3) / 4, 256, 0, stream>>>(r16, Wp2, h2f, as2, ad2, N, nWaves);
  k_agg2<<<nodeBlocks, 256, 0, stream>>>(h2f, as2, ad2, offs, col, b2, (float*)d_out, N);
}

// Round 10
// 210.806 us; speedup vs baseline: 1.9139x; 1.0246x over previous
//
#include <hip/hip_runtime.h>
#include <math.h>

#define NEG_SLOPE 0.2f
__device__ __forceinline__ float leaky(float x) { return fmaxf(x, NEG_SLOPE * x); }

typedef _Float16 f16;
typedef _Float16 f16x4 __attribute__((ext_vector_type(4)));
typedef _Float16 f16x8 __attribute__((ext_vector_type(8)));
typedef float f32x4 __attribute__((ext_vector_type(4)));

__device__ __forceinline__ int kmap(int lh, int e) {
  return (e < 4) ? lh * 4 + e : 16 + lh * 4 + (e - 4);
}

// ---------------- CSR build ----------------
__global__ void k_count(const int* __restrict__ dst, int* __restrict__ deg, int E) {
  int e = blockIdx.x * blockDim.x + threadIdx.x;
  if (e < E) atomicAdd(&deg[dst[e]], 1);
}

// ---------------- partial-reduce + weight pack (fused, independent work) ----------------
#define W1_TOT (17 * 4 * 64 * 8)
#define W2_TOT (5 * 8 * 64 * 8)
__global__ __launch_bounds__(256) void k_partial_packw(const int* __restrict__ deg,
    int* __restrict__ part, int n, int nb,
    const float* __restrict__ W1, const float* __restrict__ as1f,
    const float* __restrict__ ad1f, const float* __restrict__ W2,
    const float* __restrict__ as2f, const float* __restrict__ ad2f,
    f16* __restrict__ Wp1, f16* __restrict__ Wp2) {
  if ((int)blockIdx.x < nb) {
    __shared__ int s[256];
    int i = blockIdx.x * 256 + threadIdx.x;
    s[threadIdx.x] = (i < n) ? deg[i] : 0;
    __syncthreads();
    for (int off = 128; off > 0; off >>= 1) {
      if (threadIdx.x < off) s[threadIdx.x] += s[threadIdx.x + off];
      __syncthreads();
    }
    if (threadIdx.x == 0) part[blockIdx.x] = s[0];
  }
  int tid = blockIdx.x * 256 + threadIdx.x;
  if (tid < W1_TOT) {
    int e = tid & 7, l = (tid >> 3) & 63, ks = (tid >> 9) & 3, nt = tid >> 11;
    int lh = l >> 4, li = l & 15;
    int k = ks * 32 + kmap(lh, e);
    float v;
    if (nt < 16) {
      v = W1[k * 256 + nt * 16 + li];
    } else {
      int h = li & 7;
      const float* a = (li < 8) ? (as1f + h * 32) : (ad1f + h * 32);
      v = 0.f;
      for (int j = 0; j < 32; ++j) v += W1[k * 256 + h * 32 + j] * a[j];
    }
    Wp1[tid] = (f16)v;
  } else if (tid < W1_TOT + W2_TOT) {
    int t2 = tid - W1_TOT;
    int e = t2 & 7, l = (t2 >> 3) & 63, ks = (t2 >> 9) & 7, nt = t2 >> 12;
    int lh = l >> 4, li = l & 15;
    int k = ks * 32 + kmap(lh, e);
    float v = 0.f;
    if (nt < 4) {
      v = W2[k * 64 + nt * 16 + li];
    } else if (li == 0) {
      for (int j = 0; j < 64; ++j) v += W2[k * 64 + j] * as2f[j];
    } else if (li == 1) {
      for (int j = 0; j < 64; ++j) v += W2[k * 64 + j] * ad2f[j];
    }
    Wp2[t2] = (f16)v;
  }
}

// scans partials redundantly per block, block-local exclusive scan; zeroes cursor.
__global__ __launch_bounds__(256) void k_offs(int* __restrict__ deg,
                                              const int* __restrict__ part,
                                              int* __restrict__ offs, int n, int nb) {
  __shared__ int ps[256];
  __shared__ int s[256];
  int t = threadIdx.x;
  ps[t] = (t < nb) ? part[t] : 0;
  __syncthreads();
  for (int off = 1; off < 256; off <<= 1) {
    int u = (t >= off) ? ps[t - off] : 0;
    __syncthreads();
    ps[t] += u;
    __syncthreads();
  }
  int base = (blockIdx.x > 0) ? ps[blockIdx.x - 1] : 0;

  int i = blockIdx.x * 256 + t;
  int v = (i < n) ? deg[i] : 0;
  s[t] = v;
  __syncthreads();
  for (int off = 1; off < 256; off <<= 1) {
    int u = (t >= off) ? s[t - off] : 0;
    __syncthreads();
    s[t] += u;
    __syncthreads();
  }
  int excl = base + s[t] - v;
  if (i < n) {
    offs[i] = excl;
    deg[i] = 0;  // reset cursor for k_fill
  }
  if (i == n - 1) offs[n] = excl + v;
}

// ---------------- fused: CSR fill | MFMA GEMM1 ----------------
__global__ __launch_bounds__(256) void k_fill_gemm1(
    const int* __restrict__ src, const int* __restrict__ dst,
    const int* __restrict__ offs, int* __restrict__ cursor,
    int* __restrict__ col, int E, int fillBlocks,
    const float* __restrict__ x, const f16* __restrict__ Wp1,
    f16* __restrict__ h16, float* __restrict__ as, float* __restrict__ ad,
    int n, int nSlots) {
  if ((int)blockIdx.x < fillBlocks) {
    int e = blockIdx.x * 256 + threadIdx.x;
    if (e >= E) return;
    int d = dst[e];
    int pos = atomicAdd(&cursor[d], 1);
    col[offs[d] + pos] = src[e];
    return;
  }
  int slot = (blockIdx.x - fillBlocks) * 4 + (threadIdx.x >> 6);
  if (slot >= nSlots) return;
  int half = slot & 1;
  int wid = slot >> 1;
  int lane = threadIdx.x & 63, lh = lane >> 4, li = lane & 15;
  size_t arow = (size_t)min(wid * 16 + li, n - 1);
  f16x8 a[4];
#pragma unroll
  for (int ks = 0; ks < 4; ++ks) {
    float4 lo = *(const float4*)&x[arow * 128 + ks * 32 + lh * 4];
    float4 hi = *(const float4*)&x[arow * 128 + ks * 32 + 16 + lh * 4];
    a[ks][0] = (f16)lo.x; a[ks][1] = (f16)lo.y; a[ks][2] = (f16)lo.z; a[ks][3] = (f16)lo.w;
    a[ks][4] = (f16)hi.x; a[ks][5] = (f16)hi.y; a[ks][6] = (f16)hi.z; a[ks][7] = (f16)hi.w;
  }
  int rbase = wid * 16 + lh * 4;
  int ntBeg = half ? 8 : 0;
  int ntEnd = half ? 17 : 8;
  for (int nt = ntBeg; nt < ntEnd; ++nt) {
    f32x4 acc = {0.f, 0.f, 0.f, 0.f};
#pragma unroll
    for (int ks = 0; ks < 4; ++ks) {
      f16x8 b = *(const f16x8*)&Wp1[((nt * 4 + ks) * 64 + lane) * 8];
      acc = __builtin_amdgcn_mfma_f32_16x16x32_f16(a[ks], b, acc, 0, 0, 0);
    }
    if (nt < 16) {
#pragma unroll
      for (int r = 0; r < 4; ++r) {
        int rr = rbase + r;
        if (rr < n) h16[(size_t)rr * 256 + nt * 16 + li] = (f16)acc[r];
      }
    } else {
#pragma unroll
      for (int r = 0; r < 4; ++r) {
        int rr = rbase + r;
        if (rr < n) {
          if (li < 8) as[(size_t)rr * 8 + li] = acc[r];
          else        ad[(size_t)rr * 8 + (li - 8)] = acc[r];
        }
      }
    }
  }
}

// ---------------- fused: Layer-1 aggregation (16 nodes/block) + Layer-2 GEMM from LDS ----------------
#define RPAD 264  // 256 + 8 f16 pad: 2-way LDS bank aliasing only (free)
__global__ __launch_bounds__(256) void k_agg1_gemm2(const f16* __restrict__ h16,
    const float* __restrict__ as, const float* __restrict__ ad,
    const int* __restrict__ offs, const int* __restrict__ col,
    const float* __restrict__ b, const f16* __restrict__ Wp2,
    f16* __restrict__ h2, float* __restrict__ as2, float* __restrict__ ad2, int n) {
  __shared__ f16 rs[16][RPAD];
  int wave = threadIdx.x >> 6;
  int lane = threadIdx.x & 63;
  int head = lane >> 3;
  int c0 = lane * 4;

  // ---- phase 1: aggregate 4 nodes per wave ----
  for (int i = 0; i < 4; ++i) {
    int rl = wave * 4 + i;
    int node = blockIdx.x * 16 + rl;
    if (node >= n) {
      f16x4 z = {(f16)0.f, (f16)0.f, (f16)0.f, (f16)0.f};
      *(f16x4*)&rs[rl][c0] = z;
      continue;
    }
    node = __builtin_amdgcn_readfirstlane(node);
    int beg = offs[node], end = offs[node + 1];
    float adn = ad[node * 8 + head];

    float denom, ax, ay, az, aw;
    {  // self-loop
      float w = __expf(leaky(as[node * 8 + head] + adn));
      f16x4 g = *(const f16x4*)&h16[(size_t)node * 256 + c0];
      denom = w;
      ax = w * (float)g[0]; ay = w * (float)g[1];
      az = w * (float)g[2]; aw = w * (float)g[3];
    }
    int p = beg;
    for (; p + 8 <= end; p += 8) {
      int s[8];
#pragma unroll
      for (int j = 0; j < 8; ++j) s[j] = col[p + j];
      float e[8];
#pragma unroll
      for (int j = 0; j < 8; ++j) e[j] = as[s[j] * 8 + head];
      f16x4 g[8];
#pragma unroll
      for (int j = 0; j < 8; ++j) g[j] = *(const f16x4*)&h16[(size_t)s[j] * 256 + c0];
      float w[8];
#pragma unroll
      for (int j = 0; j < 8; ++j) w[j] = __expf(leaky(e[j] + adn));
#pragma unroll
      for (int j = 0; j < 8; ++j) {
        denom += w[j];
        ax += w[j] * (float)g[j][0]; ay += w[j] * (float)g[j][1];
        az += w[j] * (float)g[j][2]; aw += w[j] * (float)g[j][3];
      }
    }
    for (; p < end; ++p) {
      int s = col[p];
      float w = __expf(leaky(as[s * 8 + head] + adn));
      f16x4 g = *(const f16x4*)&h16[(size_t)s * 256 + c0];
      denom += w;
      ax += w * (float)g[0]; ay += w * (float)g[1];
      az += w * (float)g[2]; aw += w * (float)g[3];
    }
    float inv = 1.f / denom;
    float4 bv = *(const float4*)&b[c0];
    f16x4 o;
    o[0] = (f16)fmaxf(fmaf(ax, inv, bv.x), 0.f);
    o[1] = (f16)fmaxf(fmaf(ay, inv, bv.y), 0.f);
    o[2] = (f16)fmaxf(fmaf(az, inv, bv.z), 0.f);
    o[3] = (f16)fmaxf(fmaf(aw, inv, bv.w), 0.f);
    *(f16x4*)&rs[rl][c0] = o;
  }
  __syncthreads();

  // ---- phase 2: layer-2 GEMM for these 16 rows (A from LDS) ----
  int lh = lane >> 4, li = lane & 15;
  f16x8 a[8];
#pragma unroll
  for (int ks = 0; ks < 8; ++ks) {
    f16x4 lo = *(const f16x4*)&rs[li][ks * 32 + lh * 4];
    f16x4 hi = *(const f16x4*)&rs[li][ks * 32 + 16 + lh * 4];
    a[ks][0] = lo[0]; a[ks][1] = lo[1]; a[ks][2] = lo[2]; a[ks][3] = lo[3];
    a[ks][4] = hi[0]; a[ks][5] = hi[1]; a[ks][6] = hi[2]; a[ks][7] = hi[3];
  }
  int rbase = blockIdx.x * 16 + lh * 4;
  for (int nt = wave; nt < 5; nt += 4) {
    f32x4 acc = {0.f, 0.f, 0.f, 0.f};
#pragma unroll
    for (int ks = 0; ks < 8; ++ks) {
      f16x8 bb = *(const f16x8*)&Wp2[((nt * 8 + ks) * 64 + lane) * 8];
      acc = __builtin_amdgcn_mfma_f32_16x16x32_f16(a[ks], bb, acc, 0, 0, 0);
    }
    if (nt < 4) {
#pragma unroll
      for (int r = 0; r < 4; ++r) {
        int rr = rbase + r;
        if (rr < n) h2[(size_t)rr * 64 + nt * 16 + li] = (f16)acc[r];
      }
    } else {
#pragma unroll
      for (int r = 0; r < 4; ++r) {
        int rr = rbase + r;
        if (rr < n) {
          if (li == 0) as2[rr] = acc[r];
          else if (li == 1) ad2[rr] = acc[r];
        }
      }
    }
  }
}

// ---------------- Layer 2 aggregation: wave/node, 4 slots x 4 chains ----------------
__global__ __launch_bounds__(256) void k_agg2(const f16* __restrict__ h2,
    const float* __restrict__ as, const float* __restrict__ ad,
    const int* __restrict__ offs, const int* __restrict__ col,
    const float* __restrict__ b, float* __restrict__ out, int n) {
  int node = blockIdx.x * 4 + (threadIdx.x >> 6);
  if (node >= n) return;
  node = __builtin_amdgcn_readfirstlane(node);
  int lane = threadIdx.x & 63;
  int es = lane >> 4;
  int c = lane & 15;
  int beg = offs[node], end = offs[node + 1];
  int deg = end - beg;
  float adn = ad[node];

  float a0 = 0.f, a1 = 0.f, a2 = 0.f, a3 = 0.f, wsum = 0.f;
  if (es == 0) {
    float w = __expf(leaky(as[node] + adn));
    f16x4 g = *(const f16x4*)&h2[(size_t)node * 64 + c * 4];
    wsum = w;
    a0 = w * (float)g[0]; a1 = w * (float)g[1];
    a2 = w * (float)g[2]; a3 = w * (float)g[3];
  }
  for (int base = 0; base < deg; base += 16) {
    int s[4]; float e[4]; f16x4 g[4]; float w[4];
#pragma unroll
    for (int q = 0; q < 4; ++q) {
      int idx = base + q * 4 + es;
      s[q] = (idx < deg) ? col[beg + idx] : node;
    }
#pragma unroll
    for (int q = 0; q < 4; ++q) e[q] = as[s[q]];
#pragma unroll
    for (int q = 0; q < 4; ++q) g[q] = *(const f16x4*)&h2[(size_t)s[q] * 64 + c * 4];
#pragma unroll
    for (int q = 0; q < 4; ++q) {
      int idx = base + q * 4 + es;
      w[q] = (idx < deg) ? __expf(leaky(e[q] + adn)) : 0.f;
    }
#pragma unroll
    for (int q = 0; q < 4; ++q) {
      wsum += w[q];
      a0 += w[q] * (float)g[q][0]; a1 += w[q] * (float)g[q][1];
      a2 += w[q] * (float)g[q][2]; a3 += w[q] * (float)g[q][3];
    }
  }
  a0 += __shfl_xor(a0, 16, 64); a1 += __shfl_xor(a1, 16, 64);
  a2 += __shfl_xor(a2, 16, 64); a3 += __shfl_xor(a3, 16, 64);
  wsum += __shfl_xor(wsum, 16, 64);
  a0 += __shfl_xor(a0, 32, 64); a1 += __shfl_xor(a1, 32, 64);
  a2 += __shfl_xor(a2, 32, 64); a3 += __shfl_xor(a3, 32, 64);
  wsum += __shfl_xor(wsum, 32, 64);
  if (es == 0) {
    float inv = 1.f / wsum;
    float4 bv = *(const float4*)&b[c * 4];
    f32x4 o;
    o[0] = fmaxf(fmaf(a0, inv, bv.x), 0.f);
    o[1] = fmaxf(fmaf(a1, inv, bv.y), 0.f);
    o[2] = fmaxf(fmaf(a2, inv, bv.z), 0.f);
    o[3] = fmaxf(fmaf(a3, inv, bv.w), 0.f);
    __builtin_nontemporal_store(o, (f32x4*)&out[(size_t)node * 64 + c * 4]);
  }
}

extern "C" void kernel_launch(void* const* d_in, const int* in_sizes, int n_in,
                              void* d_out, int out_size, void* d_ws, size_t ws_size,
                              hipStream_t stream) {
  const float* x      = (const float*)d_in[0];
  const int*   ei     = (const int*)d_in[1];
  const float* W1     = (const float*)d_in[2];
  const float* a_src1 = (const float*)d_in[3];
  const float* a_dst1 = (const float*)d_in[4];
  const float* b1     = (const float*)d_in[5];
  const float* W2     = (const float*)d_in[6];
  const float* a_src2 = (const float*)d_in[7];
  const float* a_dst2 = (const float*)d_in[8];
  const float* b2     = (const float*)d_in[9];

  int N = in_sizes[0] / 128;
  int E = in_sizes[1] / 2;
  const int* srcI = ei;
  const int* dstI = ei + E;
  int nb = (N + 255) / 256;
  int packBlocks = (W1_TOT + W2_TOT + 255) / 256;
  int ppBlocks = nb > packBlocks ? nb : packBlocks;
  int nWaves = (N + 15) / 16;
  int nSlots1 = nWaves * 2;
  int fillBlocks = (E + 255) / 256;
  int gemm1Blocks = (nSlots1 + 3) / 4;
  int nodeBlocks = (N + 3) / 4;
  int aggBlocks = (N + 15) / 16;

  char* ws = (char*)d_ws;
  size_t o = 0;
  auto alloc = [&](size_t bytes) -> void* {
    void* p = ws + o;
    o += (bytes + 255) & ~(size_t)255;
    return p;
  };
  f16*   h1f    = (f16*)alloc((size_t)N * 256 * 2);
  f16*   h2f    = (f16*)alloc((size_t)N * 64 * 2);
  f16*   Wp1    = (f16*)alloc((size_t)W1_TOT * 2);
  f16*   Wp2    = (f16*)alloc((size_t)W2_TOT * 2);
  float* as1    = (float*)alloc((size_t)N * 8 * 4);
  float* ad1    = (float*)alloc((size_t)N * 8 * 4);
  float* as2    = (float*)alloc((size_t)N * 4);
  float* ad2    = (float*)alloc((size_t)N * 4);
  int*   offs   = (int*)alloc((size_t)(N + 1) * 4);
  int*   cursor = (int*)alloc((size_t)N * 4);
  int*   col    = (int*)alloc((size_t)E * 4);
  int*   part   = (int*)alloc((size_t)nb * 4);

  // CSR by dst (self-loops implicit) + weight pack fused in
  hipMemsetAsync(cursor, 0, (size_t)N * 4, stream);
  k_count<<<(E + 255) / 256, 256, 0, stream>>>(dstI, cursor, E);
  k_partial_packw<<<ppBlocks, 256, 0, stream>>>(cursor, part, N, nb,
      W1, a_src1, a_dst1, W2, a_src2, a_dst2, Wp1, Wp2);
  k_offs<<<nb, 256, 0, stream>>>(cursor, part, offs, N, nb);

  // fused: CSR fill || Layer-1 GEMM
  k_fill_gemm1<<<fillBlocks + gemm1Blocks, 256, 0, stream>>>(
      srcI, dstI, offs, cursor, col, E, fillBlocks,
      x, Wp1, h1f, as1, ad1, N, nSlots1);

  // fused: Layer-1 aggregation + Layer-2 GEMM (r16 never touches HBM)
  k_agg1_gemm2<<<aggBlocks, 256, 0, stream>>>(h1f, as1, ad1, offs, col, b1,
                                              Wp2, h2f, as2, ad2, N);

  // Layer 2 aggregation
  k_agg2<<<nodeBlocks, 256, 0, stream>>>(h2f, as2, ad2, offs, col, b2, (float*)d_out, N);
}